// Round 5
// baseline (442.577 us; speedup 1.0000x reference)
//
#include <hip/hip_runtime.h>
#include <math.h>

// RecurNN: B=256, L=256, E=100, T=255.
// x_t = W1L*left_t + W1R*right_t + b1; h_t = tanh(x_t); out = sigmoid(W2 h_254 + b2).
// For these inputs: right_t always a leaf; left_t = node t-1 (leaf at t=0).
//
// phaseA (parallel): c[b][t][:] = b1 + leaf contributions. One wave per 64 tasks;
//   indices batch-loaded (coalesced + gather), emb row read wave-uniform.
// phaseB (sequential): one wave per batch row, 255 steps, no barriers/shuffles;
//   h history in LDS (wave-uniform broadcast reads), c_t prefetched from global.
//
// KEY: weights live in 100 NAMED float2 variables per lane (rows e0=2*lane, e1).
// Named scalars always become registers (large arrays get demoted to scratch by
// AMDGPU promote-alloca — that was R1/R4's failure, VGPR_Count 92/144).

#define Bc 256
#define Lc 256
#define Ec 100
#define Tc 255
#define W1cols 200

// acc.{lo,hi} += wA.{lo,hi}*hp.lo ; then acc.{lo,hi} += wB.{lo,hi}*hp.hi
__device__ __forceinline__ void pkfma2(float2& acc, const float2 wA, const float2 wB, const float2 hp) {
    asm("v_pk_fma_f32 %0, %1, %3, %0 op_sel:[0,0,0] op_sel_hi:[1,0,1]\n\t"
        "v_pk_fma_f32 %0, %2, %3, %0 op_sel:[0,1,0] op_sel_hi:[1,1,1]"
        : "+v"(acc) : "v"(wA), "v"(wB), "v"(hp));
}

#define REP25(X) X(0) X(1) X(2) X(3) X(4) X(5) X(6) X(7) X(8) X(9) X(10) X(11) X(12) \
                 X(13) X(14) X(15) X(16) X(17) X(18) X(19) X(20) X(21) X(22) X(23) X(24)

// 100 named float2 weight registers: p{A,B,C,D}q = cols 4q..4q+3 for rows (e0,e1)
#define DECLW(q) float2 pA##q, pB##q, pC##q, pD##q;
#define LOADW(q) { float4 a4 = *(const float4*)(rA + 4*(q)); \
                   float4 b4 = *(const float4*)(rB + 4*(q)); \
                   pA##q = make_float2(a4.x, b4.x); pB##q = make_float2(a4.y, b4.y); \
                   pC##q = make_float2(a4.z, b4.z); pD##q = make_float2(a4.w, b4.w); }
// matvec step: consumes h[4q..4q+3] from rp, accumulates into accA/accB (2 chains)
#define MV(q)    { float4 h4 = *(const float4*)(rp + 4*(q)); \
                   pkfma2(accA, pA##q, pB##q, make_float2(h4.x, h4.y)); \
                   pkfma2(accB, pC##q, pD##q, make_float2(h4.z, h4.w)); }

// ======================= phaseA =======================
__global__ __launch_bounds__(256, 1)
void phaseA(const int* __restrict__ token_ids,
            const int* __restrict__ comp_left,
            const int* __restrict__ comp_right,
            const float* __restrict__ emb,
            const float* __restrict__ W1,
            const float* __restrict__ b1,
            float* __restrict__ c_ws)
{
    const int lane  = threadIdx.x & 63;
    const int chunk = (blockIdx.x << 2) | (threadIdx.x >> 6);
    if (chunk * 64 >= Bc * Tc) return;
    const int e0 = 2 * lane, e1 = e0 + 1;
    const bool act = (e0 < Ec);

    // W1R rows e0,e1 -> named registers
    const float* rA = W1 + (size_t)(act ? e0 : 0) * W1cols + Ec;
    const float* rB = W1 + (size_t)(act ? e1 : 0) * W1cols + Ec;
    REP25(DECLW)
    REP25(LOADW)
    const float2 bini = act ? *(const float2*)(b1 + e0) : make_float2(0.f, 0.f);

    // batch-load this wave's 64 tasks' indices (1 dependent level per task later)
    const int taskL = chunk * 64 + lane;
    const int cri_l = comp_right[taskL];
    const int cli_l = comp_left[taskL];
    const int b_l   = taskL / Tc;
    const int tokR_l = token_ids[b_l * Lc + min(cri_l, Lc - 1)];
    const int tokL_l = token_ids[b_l * Lc + min(cli_l, Lc - 1)];

    for (int q = 0; q < 64; ++q) {
        const int criq = __shfl(cri_l, q, 64);
        const int cliq = __shfl(cli_l, q, 64);
        const int task = chunk * 64 + q;
        float2 accA = bini, accB = make_float2(0.f, 0.f);

        if (criq < Lc) {                       // right leaf (always, these inputs)
            const int tokq = __shfl(tokR_l, q, 64);
            const float* rp = emb + (size_t)tokq * Ec;
            REP25(MV)
        }
        if (cliq < Lc) {                       // left leaf (t==0 only) — slow generic
            const int tokq = __shfl(tokL_l, q, 64);
            const float* rp = emb + (size_t)tokq * Ec;
            if (act) {
                for (int qq = 0; qq < 25; ++qq) {
                    float4 h4 = *(const float4*)(rp + 4 * qq);
                    float4 wa = *(const float4*)(W1 + (size_t)e0 * W1cols + 4 * qq);
                    float4 wb = *(const float4*)(W1 + (size_t)e1 * W1cols + 4 * qq);
                    accA.x = fmaf(wa.x, h4.x, accA.x); accA.x = fmaf(wa.y, h4.y, accA.x);
                    accB.x = fmaf(wa.z, h4.z, accB.x); accB.x = fmaf(wa.w, h4.w, accB.x);
                    accA.y = fmaf(wb.x, h4.x, accA.y); accA.y = fmaf(wb.y, h4.y, accA.y);
                    accB.y = fmaf(wb.z, h4.z, accB.y); accB.y = fmaf(wb.w, h4.w, accB.y);
                }
            }
        }
        if (act) {
            float2 o = make_float2(accA.x + accB.x, accA.y + accB.y);
            *(float2*)(c_ws + (size_t)task * Ec + e0) = o;
        }
    }
}

// ======================= phaseB =======================
__global__ __launch_bounds__(64, 1)
void phaseB(const int* __restrict__ comp_left,
            const int* __restrict__ comp_right,
            const float* __restrict__ W1,
            const float* __restrict__ W2,
            const float* __restrict__ b2,
            const float* __restrict__ c_ws,
            float* __restrict__ out)
{
    const int b    = blockIdx.x;
    const int lane = threadIdx.x;            // 0..63, single wave
    const int e0 = 2 * lane, e1 = e0 + 1;
    const bool act = (e0 < Ec);

    __shared__ __align__(16) float hist[Tc * Ec];   // 102000 B: full node history
    __shared__ int cliS[Tc], criS[Tc];

    for (int i = lane; i < Tc; i += 64) { cliS[i] = comp_left[b * Tc + i]; criS[i] = comp_right[b * Tc + i]; }
    {   // zero-init history (unwritten nodes must read as 0, per reference)
        const float4 z4 = make_float4(0.f, 0.f, 0.f, 0.f);
        for (int i = 4 * lane; i < Tc * Ec; i += 256) *(float4*)&hist[i] = z4;
    }

    // W1L rows e0,e1 -> named registers
    const float* rA = W1 + (size_t)(act ? e0 : 0) * W1cols;
    const float* rB = W1 + (size_t)(act ? e1 : 0) * W1cols;
    REP25(DECLW)
    REP25(LOADW)

    float2 w2p = make_float2(0.f, 0.f);
    if (act) w2p = make_float2(W2[e0], W2[e1]);

    const float* cb = c_ws + (size_t)b * Tc * Ec;
    float2 ccur = *(const float2*)(cb + e0);        // c_0 (garbage ok for inactive)
    __syncthreads();

    float2 h = make_float2(0.f, 0.f);
    #pragma unroll 1
    for (int t = 0; t < Tc; ++t) {
        const int tn = (t + 1 < Tc) ? t + 1 : t;
        const float2 cnext = *(const float2*)(cb + (size_t)tn * Ec + e0);  // prefetch

        const int li = __builtin_amdgcn_readfirstlane(cliS[t]);
        const int ri = __builtin_amdgcn_readfirstlane(criS[t]);
        float2 accA = ccur, accB = make_float2(0.f, 0.f);

        if (li >= Lc) {                        // left internal: general n (0 if unwritten)
            const float* rp = &hist[(li - Lc) * Ec];
            REP25(MV)
        }
        if (ri >= Lc) {                        // right internal: generic slow path (unused here)
            const float* rp = &hist[(ri - Lc) * Ec];
            if (act) {
                for (int qq = 0; qq < 25; ++qq) {
                    float4 h4 = *(const float4*)(rp + 4 * qq);
                    float4 wa = *(const float4*)(W1 + (size_t)e0 * W1cols + Ec + 4 * qq);
                    float4 wb = *(const float4*)(W1 + (size_t)e1 * W1cols + Ec + 4 * qq);
                    accA.x = fmaf(wa.x, h4.x, accA.x); accA.x = fmaf(wa.y, h4.y, accA.x);
                    accB.x = fmaf(wa.z, h4.z, accB.x); accB.x = fmaf(wa.w, h4.w, accB.x);
                    accA.y = fmaf(wb.x, h4.x, accA.y); accA.y = fmaf(wb.y, h4.y, accA.y);
                    accB.y = fmaf(wb.z, h4.z, accB.y); accB.y = fmaf(wb.w, h4.w, accB.y);
                }
            }
        }

        const float ax = accA.x + accB.x;
        const float ay = accA.y + accB.y;
        const float ux = __expf(2.f * ax);
        const float uy = __expf(2.f * ay);
        h.x = 1.f - 2.f / (ux + 1.f);          // tanh, exact identity
        h.y = 1.f - 2.f / (uy + 1.f);
        if (act) *(float2*)&hist[t * Ec + e0] = h;
        ccur = cnext;
        // single wave: DS pipe is in-order, no barrier needed
    }

    // out[b] = sigmoid(W2 . h_254 + b2)
    float s = act ? (w2p.x * h.x + w2p.y * h.y) : 0.f;
    #pragma unroll
    for (int off = 1; off < 64; off <<= 1) s += __shfl_xor(s, off, 64);
    if (lane == 0) out[b] = 1.f / (1.f + __expf(-(s + b2[0])));
}

extern "C" void kernel_launch(void* const* d_in, const int* in_sizes, int n_in,
                              void* d_out, int out_size, void* d_ws, size_t ws_size,
                              hipStream_t stream) {
    const int*   token_ids  = (const int*)  d_in[0];
    const int*   comp_left  = (const int*)  d_in[1];
    const int*   comp_right = (const int*)  d_in[2];
    const float* emb        = (const float*)d_in[3];
    const float* W1         = (const float*)d_in[4];
    const float* b1         = (const float*)d_in[5];
    const float* W2         = (const float*)d_in[6];
    const float* b2         = (const float*)d_in[7];
    float*       out        = (float*)d_out;
    float*       c_ws       = (float*)d_ws;   // B*T*E*4 = 26,112,000 B

    const int chunks = (Bc * Tc + 63) / 64;            // 1020
    phaseA<<<(chunks + 3) / 4, 256, 0, stream>>>(token_ids, comp_left, comp_right,
                                                 emb, W1, b1, c_ws);
    phaseB<<<Bc, 64, 0, stream>>>(comp_left, comp_right, W1, W2, b2, c_ws, out);
}

// Round 6
// 271.661 us; speedup vs baseline: 1.6292x; 1.6292x over previous
//
#include <hip/hip_runtime.h>
#include <math.h>

// RecurNN: B=256, L=256, E=100, T=255.
// x_t = W1L*left_t + W1R*right_t + b1; h_t = tanh(x_t); out = sigmoid(W2 h_254 + b2).
// For these inputs: right_t always a leaf; left_t = node t-1 (leaf only at t=0).
//
// Register-residency lesson (R1/R4/R5): >=200 VGPRs of weights per thread NEVER
// stays resident (arrays, named float2, inline-asm pairs all spilled). 64-100
// named SCALAR floats do promote. So: thread owns ONE weight row (100 scalars),
// outputs e-split across 128 threads (2 waves).
//
// phaseA (parallel): c[task][e] = b1[e] + W1R[e]*emb[rightleaf] (+W1L*emb leaf-left).
//   1020 blocks x 128 thr; 64 tasks/block; emb rows read wave-uniform (dwordx4).
// phaseB (sequential): 256 blocks (one per batch row) x 128 thr; thread e holds
//   W1L[e][:] in 100 scalar regs; per step: 25 uniform ds_read_b128 of h(t-1),
//   100 fma (4 chains), tanh, coalesced h write, ONE barrier (hist rows disjoint).

#define Bc 256
#define Lc 256
#define Ec 100
#define Tc 255
#define W1cols 200

#define REP25(X) X(0) X(1) X(2) X(3) X(4) X(5) X(6) X(7) X(8) X(9) X(10) X(11) X(12) \
                 X(13) X(14) X(15) X(16) X(17) X(18) X(19) X(20) X(21) X(22) X(23) X(24)

// 100 named scalar weight registers for one row (k-chunk q covers k=4q..4q+3)
#define DECLW(q) float wx##q, wy##q, wz##q, ww##q;
#define LOADW(q) { float4 t4 = *(const float4*)(wrow + 4*(q)); \
                   wx##q = t4.x; wy##q = t4.y; wz##q = t4.z; ww##q = t4.w; }
// 4 independent fma chains (a0..a3) to hide dependent-fma latency
#define MV(q)    { float4 h4 = *(const float4*)(rp + 4*(q)); \
                   a0 = fmaf(wx##q, h4.x, a0); a1 = fmaf(wy##q, h4.y, a1); \
                   a2 = fmaf(wz##q, h4.z, a2); a3 = fmaf(ww##q, h4.w, a3); }

// ======================= phaseA =======================
__global__ __launch_bounds__(128, 2)
void phaseA(const int* __restrict__ token_ids,
            const int* __restrict__ comp_left,
            const int* __restrict__ comp_right,
            const float* __restrict__ emb,
            const float* __restrict__ W1,
            const float* __restrict__ b1,
            float* __restrict__ c_ws)
{
    const int tid = threadIdx.x;
    const int e   = tid;                 // output row; active < 100
    const bool act = (e < Ec);
    const int base = blockIdx.x * 64;    // first task of this block

    __shared__ int tokR[64], tokL[64], criS[64], cliS[64];

    if (tid < 64) {
        const int task = base + tid;
        const int b  = task / Tc;        // compiler magic-mul
        const int cr = comp_right[task];
        const int cl = comp_left[task];
        criS[tid] = cr;  cliS[tid] = cl;
        tokR[tid] = token_ids[b * Lc + min(cr, Lc - 1)];
        tokL[tid] = token_ids[b * Lc + min(cl, Lc - 1)];
    }
    __syncthreads();

    // W1R row e -> 100 named scalar registers
    const float* wrow = W1 + (size_t)(act ? e : 0) * W1cols + Ec;
    REP25(DECLW)
    REP25(LOADW)
    const float b1e = act ? b1[e] : 0.f;

    #pragma unroll 2
    for (int q = 0; q < 64; ++q) {
        const int task = base + q;
        float a0 = b1e, a1 = 0.f, a2 = 0.f, a3 = 0.f;

        if (criS[q] < Lc) {              // right leaf (always, these inputs)
            const float* rp = emb + (size_t)tokR[q] * Ec;
            REP25(MV)
        }
        if (cliS[q] < Lc) {              // left leaf (t==0 only) — generic fallback
            const float* rp = emb + (size_t)tokL[q] * Ec;
            const float* wl = W1 + (size_t)(act ? e : 0) * W1cols;   // W1L row, global
            for (int qq = 0; qq < 25; ++qq) {
                float4 h4 = *(const float4*)(rp + 4 * qq);
                float4 w4 = *(const float4*)(wl + 4 * qq);
                a0 = fmaf(w4.x, h4.x, a0); a1 = fmaf(w4.y, h4.y, a1);
                a2 = fmaf(w4.z, h4.z, a2); a3 = fmaf(w4.w, h4.w, a3);
            }
        }
        if (act)
            c_ws[(size_t)task * Ec + e] = (a0 + a1) + (a2 + a3);   // coalesced
    }
}

// ======================= phaseB =======================
__global__ __launch_bounds__(128, 1)
void phaseB(const int* __restrict__ comp_left,
            const int* __restrict__ comp_right,
            const float* __restrict__ W1,
            const float* __restrict__ W2,
            const float* __restrict__ b2,
            const float* __restrict__ c_ws,
            float* __restrict__ out)
{
    const int b   = blockIdx.x;
    const int tid = threadIdx.x;         // 0..127, 2 waves
    const int e   = tid;                 // output row; active < 100
    const bool act = (e < Ec);

    __shared__ __align__(16) float hist[Tc * Ec];   // 102000 B full node history
    __shared__ int   cliS[Tc], criS[Tc];
    __shared__ float red[2];

    for (int i = tid; i < Tc; i += 128) { cliS[i] = comp_left[b * Tc + i]; criS[i] = comp_right[b * Tc + i]; }
    {   // zero-init: unwritten nodes must read as 0 (reference zero-pads buf)
        const float4 z4 = make_float4(0.f, 0.f, 0.f, 0.f);
        for (int i = tid; i < (Tc * Ec) / 4; i += 128) ((float4*)hist)[i] = z4;
    }

    // W1L row e -> 100 named scalar registers
    const float* wrow = W1 + (size_t)(act ? e : 0) * W1cols;
    REP25(DECLW)
    REP25(LOADW)
    const float w2e = act ? W2[e] : 0.f;

    const float* cb = c_ws + (size_t)b * Tc * Ec;
    float ccur = act ? cb[e] : 0.f;      // c_0
    __syncthreads();                     // hist/cli/cri ready

    float h = 0.f;
    #pragma unroll 1
    for (int t = 0; t < Tc; ++t) {
        // prefetch next c (recurrence-independent, L3-hot)
        float cnext = 0.f;
        if (act && t + 1 < Tc) cnext = cb[(size_t)(t + 1) * Ec + e];

        const int li = __builtin_amdgcn_readfirstlane(cliS[t]);
        const int ri = __builtin_amdgcn_readfirstlane(criS[t]);
        float a0 = ccur, a1 = 0.f, a2 = 0.f, a3 = 0.f;

        if (li >= Lc) {                  // left internal: wave-uniform broadcast reads
            const float* rp = &hist[(li - Lc) * Ec];
            REP25(MV)
        }
        if (ri >= Lc) {                  // right internal: generic slow path (unused here)
            const float* rp = &hist[(ri - Lc) * Ec];
            const float* wr = W1 + (size_t)(act ? e : 0) * W1cols + Ec;
            for (int qq = 0; qq < 25; ++qq) {
                float4 h4 = *(const float4*)(rp + 4 * qq);
                float4 w4 = *(const float4*)(wr + 4 * qq);
                a0 = fmaf(w4.x, h4.x, a0); a1 = fmaf(w4.y, h4.y, a1);
                a2 = fmaf(w4.z, h4.z, a2); a3 = fmaf(w4.w, h4.w, a3);
            }
        }

        const float x = (a0 + a1) + (a2 + a3);
        const float u = __expf(2.f * x);         // tanh = 1 - 2/(e^2x + 1), exact
        h = 1.f - 2.f / (u + 1.f);
        if (act) hist[t * Ec + e] = h;           // coalesced b32, disjoint from reads
        ccur = cnext;
        __syncthreads();                          // h(t) visible to both waves
    }

    // out[b] = sigmoid(W2 . h_254 + b2): 2-wave reduction
    float p = act ? w2e * h : 0.f;
    #pragma unroll
    for (int off = 32; off > 0; off >>= 1) p += __shfl_down(p, off, 64);
    if ((tid & 63) == 0) red[tid >> 6] = p;
    __syncthreads();
    if (tid == 0) out[b] = 1.f / (1.f + __expf(-(red[0] + red[1] + b2[0])));
}

extern "C" void kernel_launch(void* const* d_in, const int* in_sizes, int n_in,
                              void* d_out, int out_size, void* d_ws, size_t ws_size,
                              hipStream_t stream) {
    const int*   token_ids  = (const int*)  d_in[0];
    const int*   comp_left  = (const int*)  d_in[1];
    const int*   comp_right = (const int*)  d_in[2];
    const float* emb        = (const float*)d_in[3];
    const float* W1         = (const float*)d_in[4];
    const float* b1         = (const float*)d_in[5];
    const float* W2         = (const float*)d_in[6];
    const float* b2         = (const float*)d_in[7];
    float*       out        = (float*)d_out;
    float*       c_ws       = (float*)d_ws;   // B*T*E*4 = 26,112,000 B <= ws_size

    phaseA<<<(Bc * Tc) / 64, 128, 0, stream>>>(token_ids, comp_left, comp_right,
                                               emb, W1, b1, c_ws);
    phaseB<<<Bc, 128, 0, stream>>>(comp_left, comp_right, W1, W2, b2, c_ws, out);
}